// Round 16
// baseline (209.679 us; speedup 1.0000x reference)
//
#include <hip/hip_runtime.h>
#include <hip/hip_bf16.h>
#include <stdint.h>

#define B_ 2048
#define L_ 128
#define V_ 50000
#define D_ 128

typedef __attribute__((ext_vector_type(8))) short bf16x8;
typedef __attribute__((ext_vector_type(8))) unsigned short ushort8;
typedef __attribute__((ext_vector_type(4))) float f32x4;

__device__ inline unsigned short f2bf(float f) {
    union { float f; uint32_t u; } v; v.f = f;
    uint32_t u = v.u + 0x7FFFu + ((v.u >> 16) & 1u);   // RNE
    return (unsigned short)(u >> 16);
}
__device__ inline float bf2f(unsigned short h) {
    union { uint32_t u; float f; } v; v.u = ((uint32_t)h) << 16;
    return v.f;
}
__device__ inline float tanh_fast(float x) {
    float xc = fminf(fmaxf(x, -15.f), 15.f);
    float z = __expf(2.f * xc);
    return (z - 1.f) / (z + 1.f);
}
// load 8 fp32 -> bf16x8
__device__ inline bf16x8 ld8f(const float* p) {
    float4 x0 = *(const float4*)p;
    float4 x1 = *(const float4*)(p + 4);
    ushort8 v;
    v[0] = f2bf(x0.x); v[1] = f2bf(x0.y); v[2] = f2bf(x0.z); v[3] = f2bf(x0.w);
    v[4] = f2bf(x1.x); v[5] = f2bf(x1.y); v[6] = f2bf(x1.z); v[7] = f2bf(x1.w);
    union { ushort8 u; bf16x8 b; } c; c.u = v; return c.b;
}

// ---------------- kernel 0: aT_bf16[n][d] = bf16(attn_a[d][n]) ----------------
__global__ __launch_bounds__(256) void k_prep(const float* __restrict__ a,
                                              unsigned short* __restrict__ aT) {
    int i = blockIdx.x * 256 + threadIdx.x;   // 16384 elems
    int d = i >> 7, n = i & 127;
    aT[n * 128 + d] = f2bf(a[d * 128 + n]);
}

// ---------------- kernel 1 (FUSED): user (blocks 0..2047) + convE (2048..5172)
// k_user no longer depends on emb_bf (fp32 gather; dtype proven neutral), so
// convE runs CONCURRENTLY in the same dispatch -> its ~8us hides under the
// latency-bound user blocks. emb_bf is only read by k_logits (next dispatch).
__global__ __launch_bounds__(256) void k_fused(
    const int* __restrict__ ids, const int* __restrict__ msk,
    const float* __restrict__ emb, const unsigned short* __restrict__ aT,
    const float* __restrict__ bvec, unsigned short* __restrict__ user_bf,
    unsigned short* __restrict__ emb_bf, int use_bf) {
    __shared__ __align__(16) unsigned short lh[128 * 128];  // 32KB, swizzled
    __shared__ float l_attn[128];
    __shared__ float l_p[512];

    int bid = blockIdx.x;
    int t = threadIdx.x;

    if (bid >= B_) {
        // ---- convE part: convert 2048 fp32 -> bf16 per block
        if (use_bf) {
            size_t i = ((size_t)(bid - B_) * 256 + t) * 8;   // 3125 blocks exact
            *(ushort8*)(emb_bf + i) = (ushort8)ld8f(emb + i);
        }
        return;
    }

    // ---- user part (R15 wave-autonomous version, fp32 gather)
    int b = bid;
    int wave = t >> 6, lane = t & 63, lo = lane & 15, hi = lane >> 4;

    {
        int row = wave * 32 + (lane >> 1), half = lane & 1;
        int id = ids[b * L_ + row];
        const float* src = emb + (size_t)id * D_ + half * 64;
#pragma unroll
        for (int q = 0; q < 8; ++q) {
            bf16x8 v = ld8f(src + q * 8);
            int c = half * 64 + q * 8;
            *(bf16x8*)&lh[row * 128 + (c ^ ((row & 7) << 3))] = v;
        }
    }
    // no barrier: same-wave LDS write->read ordered by lgkmcnt

    f32x4 acc[2][8] = {};
#pragma unroll
    for (int kk = 0; kk < 4; ++kk) {
        int kc = kk * 32 + hi * 8;
        bf16x8 afr[2];
#pragma unroll
        for (int mi = 0; mi < 2; ++mi) {
            int row = wave * 32 + mi * 16 + lo;
            afr[mi] = *(const bf16x8*)&lh[row * 128 + (kc ^ ((row & 7) << 3))];
        }
#pragma unroll
        for (int nj = 0; nj < 8; ++nj) {
            int col = nj * 16 + lo;
            bf16x8 bfr = *(const bf16x8*)(aT + col * 128 + kc);   // L1-resident
            acc[0][nj] = __builtin_amdgcn_mfma_f32_16x16x32_bf16(afr[0], bfr, acc[0][nj], 0, 0, 0);
            acc[1][nj] = __builtin_amdgcn_mfma_f32_16x16x32_bf16(afr[1], bfr, acc[1][nj], 0, 0, 0);
        }
    }

    float bv[8];
#pragma unroll
    for (int nj = 0; nj < 8; ++nj) bv[nj] = bvec[nj * 16 + lo];
#pragma unroll
    for (int mi = 0; mi < 2; ++mi) {
#pragma unroll
        for (int reg = 0; reg < 4; ++reg) {
            float p = 0.f;
#pragma unroll
            for (int nj = 0; nj < 8; ++nj) p += tanh_fast(acc[mi][nj][reg]) * bv[nj];
            p += __shfl_xor(p, 1); p += __shfl_xor(p, 2);
            p += __shfl_xor(p, 4); p += __shfl_xor(p, 8);
            int row = wave * 32 + mi * 16 + hi * 4 + reg;
            if (lo == 0) {
                float at = 0.f;
                if (msk[b * L_ + row]) at = 1.f / (1.f + __expf(-p));
                l_attn[row] = at;
            }
        }
    }

    {
        float s0 = 0.f, s1 = 0.f;
        int d0 = 2 * lane;
#pragma unroll
        for (int j = 0; j < 32; ++j) {
            int r = wave * 32 + j;
            float a = l_attn[r];
            int c = d0 ^ ((r & 7) << 3);
            s0 += a * bf2f(lh[r * 128 + c]);
            s1 += a * bf2f(lh[r * 128 + c + 1]);
        }
        l_p[wave * 128 + d0] = s0;
        l_p[wave * 128 + d0 + 1] = s1;
    }
    __syncthreads();

    if (t < 128) {
        float u = l_p[t] + l_p[128 + t] + l_p[256 + t] + l_p[384 + t];
        user_bf[b * 128 + t] = f2bf(u);
    }
}

// ---------------- kernel 2: logits = user_bf16 @ emb^T + bias ----------------
// R12 geometry (6256 blocks of 32 cols x 512 rows: 24.4 blocks/CU, ~5 resident,
// 16KB LDS, ~100 VGPR; passed, 0 bank conflicts) + R14's winning NONTEMPORAL
// full-line stores. Tests whether NT write BW scales with outstanding-store depth.
__global__ __launch_bounds__(256) void k_logits(
    const unsigned short* __restrict__ user_bf, const float* __restrict__ emb,
    const unsigned short* __restrict__ emb_bf,
    const float* __restrict__ bias, float* __restrict__ out, int use_bf) {
    __shared__ __align__(16) float lt[4][32 * 32];   // per-wave 4KB C-tile

    int t = threadIdx.x;
    int wave = t >> 6, lane = t & 63, lo = lane & 15, hi = lane >> 4;
    int n0 = blockIdx.x * 32;      // 1564 * 32 = 50048 >= V_
    int r0 = blockIdx.y * 512;     // 4 row-quarters

    bf16x8 efr[2][4];
#pragma unroll
    for (int cg = 0; cg < 2; ++cg) {
        int col = n0 + cg * 16 + lo;
        int cc = (col < V_) ? col : 0;          // emb row 0 is all zeros
        if (use_bf) {
            const unsigned short* ep = emb_bf + (size_t)cc * 128 + hi * 8;
#pragma unroll
            for (int kk = 0; kk < 4; ++kk)
                efr[cg][kk] = *(const bf16x8*)(ep + kk * 32);
        } else {
            const float* ef = emb + (size_t)cc * 128 + hi * 8;
#pragma unroll
            for (int kk = 0; kk < 4; ++kk)
                efr[cg][kk] = ld8f(ef + kk * 32);
        }
    }

    float4 bb[2];
#pragma unroll
    for (int cg = 0; cg < 2; ++cg) {
        int n = n0 + cg * 16 + hi * 4;
        if (n + 3 < V_) {
            bb[cg] = *(const float4*)(bias + n);
        } else {
            bb[cg].x = (n + 0 < V_) ? bias[n + 0] : 0.f;
            bb[cg].y = (n + 1 < V_) ? bias[n + 1] : 0.f;
            bb[cg].z = (n + 2 < V_) ? bias[n + 2] : 0.f;
            bb[cg].w = (n + 3 < V_) ? bias[n + 3] : 0.f;
        }
    }

    float* myt = lt[wave];

#pragma unroll 1
    for (int ci = 0; ci < 4; ++ci) {
        int c = wave + ci * 4;
        int rbase = r0 + c * 32;

        bf16x8 ufr[2][4];
#pragma unroll
        for (int mi = 0; mi < 2; ++mi) {
            const unsigned short* up = user_bf + (size_t)(rbase + mi * 16 + lo) * 128 + hi * 8;
#pragma unroll
            for (int kk = 0; kk < 4; ++kk)
                ufr[mi][kk] = *(const bf16x8*)(up + kk * 32);
        }

        f32x4 acc[2][2] = {};   // [cg][mi]
#pragma unroll
        for (int kk = 0; kk < 4; ++kk)
#pragma unroll
            for (int cg = 0; cg < 2; ++cg)
#pragma unroll
                for (int mi = 0; mi < 2; ++mi)
                    acc[cg][mi] = __builtin_amdgcn_mfma_f32_16x16x32_bf16(
                        efr[cg][kk], ufr[mi][kk], acc[cg][mi], 0, 0, 0);

        // epilogue A: acc+bias -> LDS [b_loc 0..31][chunk 0..7], XOR swizzle
#pragma unroll
        for (int mi = 0; mi < 2; ++mi) {
            int b_loc = mi * 16 + lo;
#pragma unroll
            for (int cg = 0; cg < 2; ++cg) {
                f32x4 o;
                o[0] = acc[cg][mi][0] + bb[cg].x;
                o[1] = acc[cg][mi][1] + bb[cg].y;
                o[2] = acc[cg][mi][2] + bb[cg].z;
                o[3] = acc[cg][mi][3] + bb[cg].w;
                int ch = (cg * 4 + hi) ^ (b_loc & 7);
                *(f32x4*)&myt[b_loc * 32 + ch * 4] = o;
            }
        }

        // epilogue B: dense read-back; per instr 8 rows x 128B full lines, NT
#pragma unroll
        for (int it = 0; it < 4; ++it) {
            int b_loc = it * 8 + (lane >> 3);
            int k = lane & 7;
            f32x4 v = *(const f32x4*)&myt[b_loc * 32 + ((k ^ (b_loc & 7)) * 4)];
            int n = n0 + k * 4;
            if (n + 3 < V_) {
                __builtin_nontemporal_store(v, (f32x4*)(out + (size_t)(rbase + b_loc) * V_ + n));
            } else {
                float* op = out + (size_t)(rbase + b_loc) * V_;
                if (n + 0 < V_) op[n + 0] = v[0];
                if (n + 1 < V_) op[n + 1] = v[1];
                if (n + 2 < V_) op[n + 2] = v[2];
                if (n + 3 < V_) op[n + 3] = v[3];
            }
        }
    }
}

extern "C" void kernel_launch(void* const* d_in, const int* in_sizes, int n_in,
                              void* d_out, int out_size, void* d_ws, size_t ws_size,
                              hipStream_t stream) {
    const int* ids      = (const int*)d_in[0];
    const int* msk      = (const int*)d_in[1];
    const float* emb    = (const float*)d_in[2];
    const float* attn_a = (const float*)d_in[3];
    const float* attn_b = (const float*)d_in[4];
    const float* rbias  = (const float*)d_in[5];
    float* out = (float*)d_out;

    unsigned short* aT      = (unsigned short*)d_ws;                     // 32 KB
    unsigned short* user_bf = (unsigned short*)((char*)d_ws + 32768);    // 512 KB
    unsigned short* emb_bf  = (unsigned short*)((char*)d_ws + 32768 + 524288);  // 12.8 MB
    int use_bf = (ws_size >= (size_t)(32768 + 524288 + 12800000)) ? 1 : 0;

    k_prep<<<64, 256, 0, stream>>>(attn_a, aT);
    k_fused<<<B_ + (use_bf ? 3125 : 0), 256, 0, stream>>>(ids, msk, emb, aT, attn_b,
                                                          user_bf, emb_bf, use_bf);
    k_logits<<<dim3(1564, 4), 256, 0, stream>>>(user_bf, emb, emb_bf, rbias, out, use_bf);
}

// Round 17
// 174.633 us; speedup vs baseline: 1.2007x; 1.2007x over previous
//
#include <hip/hip_runtime.h>
#include <hip/hip_bf16.h>
#include <stdint.h>

#define B_ 2048
#define L_ 128
#define V_ 50000
#define D_ 128

typedef __attribute__((ext_vector_type(8))) short bf16x8;
typedef __attribute__((ext_vector_type(8))) unsigned short ushort8;
typedef __attribute__((ext_vector_type(4))) float f32x4;

__device__ inline unsigned short f2bf(float f) {
    union { float f; uint32_t u; } v; v.f = f;
    uint32_t u = v.u + 0x7FFFu + ((v.u >> 16) & 1u);   // RNE
    return (unsigned short)(u >> 16);
}
__device__ inline float bf2f(unsigned short h) {
    union { uint32_t u; float f; } v; v.u = ((uint32_t)h) << 16;
    return v.f;
}
__device__ inline float tanh_fast(float x) {
    float xc = fminf(fmaxf(x, -15.f), 15.f);
    float z = __expf(2.f * xc);
    return (z - 1.f) / (z + 1.f);
}
// load 8 fp32 -> bf16x8 (fallback path only)
__device__ inline bf16x8 ld8f(const float* p) {
    float4 x0 = *(const float4*)p;
    float4 x1 = *(const float4*)(p + 4);
    ushort8 v;
    v[0] = f2bf(x0.x); v[1] = f2bf(x0.y); v[2] = f2bf(x0.z); v[3] = f2bf(x0.w);
    v[4] = f2bf(x1.x); v[5] = f2bf(x1.y); v[6] = f2bf(x1.z); v[7] = f2bf(x1.w);
    union { ushort8 u; bf16x8 b; } c; c.u = v; return c.b;
}

// ---------------- kernel 0: fused emb->bf16 convert + aT transpose ----------------
__global__ __launch_bounds__(256) void k_pre(const float* __restrict__ emb,
                                             unsigned short* __restrict__ emb_bf,
                                             const float* __restrict__ a,
                                             unsigned short* __restrict__ aT,
                                             int use_bf) {
    int bid = blockIdx.x;
    if (use_bf && bid < 3125) {
        size_t i = ((size_t)bid * 256 + threadIdx.x) * 8;  // 6,400,000 elems exact
        float4 x0 = *(const float4*)(emb + i);
        float4 x1 = *(const float4*)(emb + i + 4);
        ushort8 v;
        v[0] = f2bf(x0.x); v[1] = f2bf(x0.y); v[2] = f2bf(x0.z); v[3] = f2bf(x0.w);
        v[4] = f2bf(x1.x); v[5] = f2bf(x1.y); v[6] = f2bf(x1.z); v[7] = f2bf(x1.w);
        *(ushort8*)(emb_bf + i) = v;
    } else if (!use_bf || bid == 3125) {
#pragma unroll 4
        for (int j = threadIdx.x; j < 16384; j += 256) {
            int d = j >> 7, n = j & 127;
            aT[n * 128 + d] = f2bf(a[d * 128 + n]);
        }
    }
}

// ---------------- kernel 1: user_bf16[b][d] — WAVE-AUTONOMOUS (R15, best) ----
__global__ __launch_bounds__(256) void k_user(
    const int* __restrict__ ids, const int* __restrict__ msk,
    const float* __restrict__ emb, const unsigned short* __restrict__ emb_bf,
    const unsigned short* __restrict__ aT,
    const float* __restrict__ bvec, unsigned short* __restrict__ user_bf,
    int use_bf) {
    __shared__ __align__(16) unsigned short lh[128 * 128];  // 32KB, swizzled
    __shared__ float l_attn[128];
    __shared__ float l_p[512];                              // 4 waves x 128 d

    int b = blockIdx.x;
    int t = threadIdx.x;
    int wave = t >> 6, lane = t & 63, lo = lane & 15, hi = lane >> 4;

    // ---- stage: wave w gathers its rows w*32 .. w*32+31 (2 lanes/row)
    {
        int row = wave * 32 + (lane >> 1), half = lane & 1;
        int id = ids[b * L_ + row];
        if (use_bf) {
            const unsigned short* src = emb_bf + (size_t)id * D_ + half * 64;
#pragma unroll
            for (int q = 0; q < 8; ++q) {
                ushort8 v = *(const ushort8*)(src + q * 8);
                int c = half * 64 + q * 8;
                *(ushort8*)&lh[row * 128 + (c ^ ((row & 7) << 3))] = v;
            }
        } else {
            const float* src = emb + (size_t)id * D_ + half * 64;
#pragma unroll
            for (int q = 0; q < 8; ++q) {
                bf16x8 v = ld8f(src + q * 8);
                int c = half * 64 + q * 8;
                *(bf16x8*)&lh[row * 128 + (c ^ ((row & 7) << 3))] = v;
            }
        }
    }
    // no barrier: same-wave LDS write->read ordered by lgkmcnt

    f32x4 acc[2][8] = {};
#pragma unroll
    for (int kk = 0; kk < 4; ++kk) {
        int kc = kk * 32 + hi * 8;
        bf16x8 afr[2];
#pragma unroll
        for (int mi = 0; mi < 2; ++mi) {
            int row = wave * 32 + mi * 16 + lo;
            afr[mi] = *(const bf16x8*)&lh[row * 128 + (kc ^ ((row & 7) << 3))];
        }
#pragma unroll
        for (int nj = 0; nj < 8; ++nj) {
            int col = nj * 16 + lo;
            bf16x8 bfr = *(const bf16x8*)(aT + col * 128 + kc);   // L1-resident
            acc[0][nj] = __builtin_amdgcn_mfma_f32_16x16x32_bf16(afr[0], bfr, acc[0][nj], 0, 0, 0);
            acc[1][nj] = __builtin_amdgcn_mfma_f32_16x16x32_bf16(afr[1], bfr, acc[1][nj], 0, 0, 0);
        }
    }

    float bv[8];
#pragma unroll
    for (int nj = 0; nj < 8; ++nj) bv[nj] = bvec[nj * 16 + lo];
#pragma unroll
    for (int mi = 0; mi < 2; ++mi) {
#pragma unroll
        for (int reg = 0; reg < 4; ++reg) {
            float p = 0.f;
#pragma unroll
            for (int nj = 0; nj < 8; ++nj) p += tanh_fast(acc[mi][nj][reg]) * bv[nj];
            p += __shfl_xor(p, 1); p += __shfl_xor(p, 2);
            p += __shfl_xor(p, 4); p += __shfl_xor(p, 8);
            int row = wave * 32 + mi * 16 + hi * 4 + reg;
            if (lo == 0) {
                float at = 0.f;
                if (msk[b * L_ + row]) at = 1.f / (1.f + __expf(-p));
                l_attn[row] = at;
            }
        }
    }

    {
        float s0 = 0.f, s1 = 0.f;
        int d0 = 2 * lane;
#pragma unroll
        for (int j = 0; j < 32; ++j) {
            int r = wave * 32 + j;
            float a = l_attn[r];
            int c = d0 ^ ((r & 7) << 3);
            s0 += a * bf2f(lh[r * 128 + c]);
            s1 += a * bf2f(lh[r * 128 + c + 1]);
        }
        l_p[wave * 128 + d0] = s0;
        l_p[wave * 128 + d0 + 1] = s1;
    }
    __syncthreads();   // the ONE barrier

    if (t < 128) {
        float u = l_p[t] + l_p[128 + t] + l_p[256 + t] + l_p[384 + t];
        user_bf[b * 128 + t] = f2bf(u);
    }
}

// ---------------- kernel 2: logits = user_bf16 @ emb^T + bias ----------------
// R14/R15 structure, NT full-line stores. SINGLE CHANGE: grid (782, 2) — each
// block covers 32 row-chunks (1024 rows) instead of 64, doubling block count
// (6.1/CU vs 3.05/CU) to shrink the grid-tail from ~30% to ~14%.
__global__ __launch_bounds__(256) void k_logits(
    const unsigned short* __restrict__ user_bf, const float* __restrict__ emb,
    const unsigned short* __restrict__ emb_bf,
    const float* __restrict__ bias, float* __restrict__ out, int use_bf) {
    __shared__ __align__(16) float lt[4][32 * 64];   // per-wave C-tile (32KB total)

    int t = threadIdx.x;
    int wave = t >> 6, lane = t & 63, lo = lane & 15, hi = lane >> 4;
    int n0 = blockIdx.x * 64;   // 782 * 64 = 50048 >= V_
    int r0 = blockIdx.y * 1024; // 2 row-halves

    bf16x8 efr[4][4];
#pragma unroll
    for (int cg = 0; cg < 4; ++cg) {
        int col = n0 + cg * 16 + lo;
        int cc = (col < V_) ? col : 0;          // emb row 0 is all zeros
        const unsigned short* ep = emb_bf + (size_t)cc * 128 + hi * 8;
        if (use_bf) {
#pragma unroll
            for (int kk = 0; kk < 4; ++kk)
                efr[cg][kk] = *(const bf16x8*)(ep + kk * 32);
        } else {
            const float* ef = emb + (size_t)cc * 128 + hi * 8;
#pragma unroll
            for (int kk = 0; kk < 4; ++kk)
                efr[cg][kk] = ld8f(ef + kk * 32);
        }
    }

    float4 bb[4];
#pragma unroll
    for (int cg = 0; cg < 4; ++cg) {
        int n = n0 + cg * 16 + hi * 4;
        if (n + 3 < V_) {
            bb[cg] = *(const float4*)(bias + n);
        } else {
            bb[cg].x = (n + 0 < V_) ? bias[n + 0] : 0.f;
            bb[cg].y = (n + 1 < V_) ? bias[n + 1] : 0.f;
            bb[cg].z = (n + 2 < V_) ? bias[n + 2] : 0.f;
            bb[cg].w = (n + 3 < V_) ? bias[n + 3] : 0.f;
        }
    }

    float* myt = lt[wave];

    // 32 row-chunks of 32; wave w takes chunks w, w+4, ...
#pragma unroll 1
    for (int c = wave; c < 32; c += 4) {
        int rbase = r0 + c * 32;

        bf16x8 ufr[2][4];
#pragma unroll
        for (int mi = 0; mi < 2; ++mi) {
            const unsigned short* up = user_bf + (size_t)(rbase + mi * 16 + lo) * 128 + hi * 8;
#pragma unroll
            for (int kk = 0; kk < 4; ++kk)
                ufr[mi][kk] = *(const bf16x8*)(up + kk * 32);
        }

        f32x4 acc[4][2] = {};   // [cg][mi]
#pragma unroll
        for (int kk = 0; kk < 4; ++kk)
#pragma unroll
            for (int cg = 0; cg < 4; ++cg)
#pragma unroll
                for (int mi = 0; mi < 2; ++mi)
                    acc[cg][mi] = __builtin_amdgcn_mfma_f32_16x16x32_bf16(
                        efr[cg][kk], ufr[mi][kk], acc[cg][mi], 0, 0, 0);

        // epilogue A: acc+bias -> LDS tile [b_loc][n_loc], chunk-XOR swizzle
#pragma unroll
        for (int mi = 0; mi < 2; ++mi) {
            int b_loc = mi * 16 + lo;
#pragma unroll
            for (int cg = 0; cg < 4; ++cg) {
                f32x4 o;
                o[0] = acc[cg][mi][0] + bb[cg].x;
                o[1] = acc[cg][mi][1] + bb[cg].y;
                o[2] = acc[cg][mi][2] + bb[cg].z;
                o[3] = acc[cg][mi][3] + bb[cg].w;
                int ch = (cg * 4 + hi) ^ (b_loc & 15);
                *(f32x4*)&myt[b_loc * 64 + ch * 4] = o;
            }
        }

        // epilogue B: dense read-back + NT full-line stores
#pragma unroll
        for (int it = 0; it < 8; ++it) {
            int b_loc = it * 4 + hi;
            f32x4 v = *(const f32x4*)&myt[b_loc * 64 + ((lo ^ (b_loc & 15)) * 4)];
            int n = n0 + lo * 4;
            if (n + 3 < V_) {
                __builtin_nontemporal_store(v, (f32x4*)(out + (size_t)(rbase + b_loc) * V_ + n));
            }
        }
    }
}

extern "C" void kernel_launch(void* const* d_in, const int* in_sizes, int n_in,
                              void* d_out, int out_size, void* d_ws, size_t ws_size,
                              hipStream_t stream) {
    const int* ids      = (const int*)d_in[0];
    const int* msk      = (const int*)d_in[1];
    const float* emb    = (const float*)d_in[2];
    const float* attn_a = (const float*)d_in[3];
    const float* attn_b = (const float*)d_in[4];
    const float* rbias  = (const float*)d_in[5];
    float* out = (float*)d_out;

    unsigned short* aT      = (unsigned short*)d_ws;                     // 32 KB
    unsigned short* user_bf = (unsigned short*)((char*)d_ws + 32768);    // 512 KB
    unsigned short* emb_bf  = (unsigned short*)((char*)d_ws + 32768 + 524288);  // 12.8 MB
    int use_bf = (ws_size >= (size_t)(32768 + 524288 + 12800000)) ? 1 : 0;

    k_pre<<<use_bf ? 3126 : 1, 256, 0, stream>>>(emb, emb_bf, attn_a, aT, use_bf);
    k_user<<<2048, 256, 0, stream>>>(ids, msk, emb, emb_bf, aT, attn_b, user_bf, use_bf);
    k_logits<<<dim3(782, 2), 256, 0, stream>>>(user_bf, emb, emb_bf, rbias, out, use_bf);
}

// Round 18
// 174.083 us; speedup vs baseline: 1.2045x; 1.0032x over previous
//
#include <hip/hip_runtime.h>
#include <hip/hip_bf16.h>
#include <stdint.h>

#define B_ 2048
#define L_ 128
#define V_ 50000
#define D_ 128

typedef __attribute__((ext_vector_type(8))) short bf16x8;
typedef __attribute__((ext_vector_type(8))) unsigned short ushort8;
typedef __attribute__((ext_vector_type(4))) float f32x4;

__device__ inline unsigned short f2bf(float f) {
    union { float f; uint32_t u; } v; v.f = f;
    uint32_t u = v.u + 0x7FFFu + ((v.u >> 16) & 1u);   // RNE
    return (unsigned short)(u >> 16);
}
__device__ inline float bf2f(unsigned short h) {
    union { uint32_t u; float f; } v; v.u = ((uint32_t)h) << 16;
    return v.f;
}
__device__ inline float tanh_fast(float x) {
    float xc = fminf(fmaxf(x, -15.f), 15.f);
    float z = __expf(2.f * xc);
    return (z - 1.f) / (z + 1.f);
}
// load 8 fp32 -> bf16x8 (fallback path only)
__device__ inline bf16x8 ld8f(const float* p) {
    float4 x0 = *(const float4*)p;
    float4 x1 = *(const float4*)(p + 4);
    ushort8 v;
    v[0] = f2bf(x0.x); v[1] = f2bf(x0.y); v[2] = f2bf(x0.z); v[3] = f2bf(x0.w);
    v[4] = f2bf(x1.x); v[5] = f2bf(x1.y); v[6] = f2bf(x1.z); v[7] = f2bf(x1.w);
    union { ushort8 u; bf16x8 b; } c; c.u = v; return c.b;
}

// ---------------- kernel 0: fused emb->bf16 convert + aT transpose ----------------
__global__ __launch_bounds__(256) void k_pre(const float* __restrict__ emb,
                                             unsigned short* __restrict__ emb_bf,
                                             const float* __restrict__ a,
                                             unsigned short* __restrict__ aT,
                                             int use_bf) {
    int bid = blockIdx.x;
    if (use_bf && bid < 3125) {
        size_t i = ((size_t)bid * 256 + threadIdx.x) * 8;  // 6,400,000 elems exact
        float4 x0 = *(const float4*)(emb + i);
        float4 x1 = *(const float4*)(emb + i + 4);
        ushort8 v;
        v[0] = f2bf(x0.x); v[1] = f2bf(x0.y); v[2] = f2bf(x0.z); v[3] = f2bf(x0.w);
        v[4] = f2bf(x1.x); v[5] = f2bf(x1.y); v[6] = f2bf(x1.z); v[7] = f2bf(x1.w);
        *(ushort8*)(emb_bf + i) = v;
    } else if (!use_bf || bid == 3125) {
#pragma unroll 4
        for (int j = threadIdx.x; j < 16384; j += 256) {
            int d = j >> 7, n = j & 127;
            aT[n * 128 + d] = f2bf(a[d * 128 + n]);
        }
    }
}

// ---------------- kernel 1: user_bf16[b][d] — WAVE-AUTONOMOUS (R15, best) ----
__global__ __launch_bounds__(256) void k_user(
    const int* __restrict__ ids, const int* __restrict__ msk,
    const float* __restrict__ emb, const unsigned short* __restrict__ emb_bf,
    const unsigned short* __restrict__ aT,
    const float* __restrict__ bvec, unsigned short* __restrict__ user_bf,
    int use_bf) {
    __shared__ __align__(16) unsigned short lh[128 * 128];  // 32KB, swizzled
    __shared__ float l_attn[128];
    __shared__ float l_p[512];                              // 4 waves x 128 d

    int b = blockIdx.x;
    int t = threadIdx.x;
    int wave = t >> 6, lane = t & 63, lo = lane & 15, hi = lane >> 4;

    // ---- stage: wave w gathers its rows w*32 .. w*32+31 (2 lanes/row)
    {
        int row = wave * 32 + (lane >> 1), half = lane & 1;
        int id = ids[b * L_ + row];
        if (use_bf) {
            const unsigned short* src = emb_bf + (size_t)id * D_ + half * 64;
#pragma unroll
            for (int q = 0; q < 8; ++q) {
                ushort8 v = *(const ushort8*)(src + q * 8);
                int c = half * 64 + q * 8;
                *(ushort8*)&lh[row * 128 + (c ^ ((row & 7) << 3))] = v;
            }
        } else {
            const float* src = emb + (size_t)id * D_ + half * 64;
#pragma unroll
            for (int q = 0; q < 8; ++q) {
                bf16x8 v = ld8f(src + q * 8);
                int c = half * 64 + q * 8;
                *(bf16x8*)&lh[row * 128 + (c ^ ((row & 7) << 3))] = v;
            }
        }
    }
    // no barrier: same-wave LDS write->read ordered by lgkmcnt

    f32x4 acc[2][8] = {};
#pragma unroll
    for (int kk = 0; kk < 4; ++kk) {
        int kc = kk * 32 + hi * 8;
        bf16x8 afr[2];
#pragma unroll
        for (int mi = 0; mi < 2; ++mi) {
            int row = wave * 32 + mi * 16 + lo;
            afr[mi] = *(const bf16x8*)&lh[row * 128 + (kc ^ ((row & 7) << 3))];
        }
#pragma unroll
        for (int nj = 0; nj < 8; ++nj) {
            int col = nj * 16 + lo;
            bf16x8 bfr = *(const bf16x8*)(aT + col * 128 + kc);   // L1-resident
            acc[0][nj] = __builtin_amdgcn_mfma_f32_16x16x32_bf16(afr[0], bfr, acc[0][nj], 0, 0, 0);
            acc[1][nj] = __builtin_amdgcn_mfma_f32_16x16x32_bf16(afr[1], bfr, acc[1][nj], 0, 0, 0);
        }
    }

    float bv[8];
#pragma unroll
    for (int nj = 0; nj < 8; ++nj) bv[nj] = bvec[nj * 16 + lo];
#pragma unroll
    for (int mi = 0; mi < 2; ++mi) {
#pragma unroll
        for (int reg = 0; reg < 4; ++reg) {
            float p = 0.f;
#pragma unroll
            for (int nj = 0; nj < 8; ++nj) p += tanh_fast(acc[mi][nj][reg]) * bv[nj];
            p += __shfl_xor(p, 1); p += __shfl_xor(p, 2);
            p += __shfl_xor(p, 4); p += __shfl_xor(p, 8);
            int row = wave * 32 + mi * 16 + hi * 4 + reg;
            if (lo == 0) {
                float at = 0.f;
                if (msk[b * L_ + row]) at = 1.f / (1.f + __expf(-p));
                l_attn[row] = at;
            }
        }
    }

    {
        float s0 = 0.f, s1 = 0.f;
        int d0 = 2 * lane;
#pragma unroll
        for (int j = 0; j < 32; ++j) {
            int r = wave * 32 + j;
            float a = l_attn[r];
            int c = d0 ^ ((r & 7) << 3);
            s0 += a * bf2f(lh[r * 128 + c]);
            s1 += a * bf2f(lh[r * 128 + c + 1]);
        }
        l_p[wave * 128 + d0] = s0;
        l_p[wave * 128 + d0 + 1] = s1;
    }
    __syncthreads();   // the ONE barrier

    if (t < 128) {
        float u = l_p[t] + l_p[128 + t] + l_p[256 + t] + l_p[384 + t];
        user_bf[b * 128 + t] = f2bf(u);
    }
}

// ---------------- kernel 2: logits = user_bf16 @ emb^T + bias ----------------
// R17 structure, NT full-line stores. SINGLE CHANGE: grid (782, 4) — each block
// covers 16 row-chunks (512 rows); 3128 blocks = 12.2/CU -> tail ~8%.
__global__ __launch_bounds__(256) void k_logits(
    const unsigned short* __restrict__ user_bf, const float* __restrict__ emb,
    const unsigned short* __restrict__ emb_bf,
    const float* __restrict__ bias, float* __restrict__ out, int use_bf) {
    __shared__ __align__(16) float lt[4][32 * 64];   // per-wave C-tile (32KB total)

    int t = threadIdx.x;
    int wave = t >> 6, lane = t & 63, lo = lane & 15, hi = lane >> 4;
    int n0 = blockIdx.x * 64;   // 782 * 64 = 50048 >= V_
    int r0 = blockIdx.y * 512;  // 4 row-quarters

    bf16x8 efr[4][4];
#pragma unroll
    for (int cg = 0; cg < 4; ++cg) {
        int col = n0 + cg * 16 + lo;
        int cc = (col < V_) ? col : 0;          // emb row 0 is all zeros
        const unsigned short* ep = emb_bf + (size_t)cc * 128 + hi * 8;
        if (use_bf) {
#pragma unroll
            for (int kk = 0; kk < 4; ++kk)
                efr[cg][kk] = *(const bf16x8*)(ep + kk * 32);
        } else {
            const float* ef = emb + (size_t)cc * 128 + hi * 8;
#pragma unroll
            for (int kk = 0; kk < 4; ++kk)
                efr[cg][kk] = ld8f(ef + kk * 32);
        }
    }

    float4 bb[4];
#pragma unroll
    for (int cg = 0; cg < 4; ++cg) {
        int n = n0 + cg * 16 + hi * 4;
        if (n + 3 < V_) {
            bb[cg] = *(const float4*)(bias + n);
        } else {
            bb[cg].x = (n + 0 < V_) ? bias[n + 0] : 0.f;
            bb[cg].y = (n + 1 < V_) ? bias[n + 1] : 0.f;
            bb[cg].z = (n + 2 < V_) ? bias[n + 2] : 0.f;
            bb[cg].w = (n + 3 < V_) ? bias[n + 3] : 0.f;
        }
    }

    float* myt = lt[wave];

    // 16 row-chunks of 32; wave w takes chunks w, w+4, w+8, w+12
#pragma unroll 1
    for (int c = wave; c < 16; c += 4) {
        int rbase = r0 + c * 32;

        bf16x8 ufr[2][4];
#pragma unroll
        for (int mi = 0; mi < 2; ++mi) {
            const unsigned short* up = user_bf + (size_t)(rbase + mi * 16 + lo) * 128 + hi * 8;
#pragma unroll
            for (int kk = 0; kk < 4; ++kk)
                ufr[mi][kk] = *(const bf16x8*)(up + kk * 32);
        }

        f32x4 acc[4][2] = {};   // [cg][mi]
#pragma unroll
        for (int kk = 0; kk < 4; ++kk)
#pragma unroll
            for (int cg = 0; cg < 4; ++cg)
#pragma unroll
                for (int mi = 0; mi < 2; ++mi)
                    acc[cg][mi] = __builtin_amdgcn_mfma_f32_16x16x32_bf16(
                        efr[cg][kk], ufr[mi][kk], acc[cg][mi], 0, 0, 0);

        // epilogue A: acc+bias -> LDS tile [b_loc][n_loc], chunk-XOR swizzle
#pragma unroll
        for (int mi = 0; mi < 2; ++mi) {
            int b_loc = mi * 16 + lo;
#pragma unroll
            for (int cg = 0; cg < 4; ++cg) {
                f32x4 o;
                o[0] = acc[cg][mi][0] + bb[cg].x;
                o[1] = acc[cg][mi][1] + bb[cg].y;
                o[2] = acc[cg][mi][2] + bb[cg].z;
                o[3] = acc[cg][mi][3] + bb[cg].w;
                int ch = (cg * 4 + hi) ^ (b_loc & 15);
                *(f32x4*)&myt[b_loc * 64 + ch * 4] = o;
            }
        }

        // epilogue B: dense read-back + NT full-line stores
#pragma unroll
        for (int it = 0; it < 8; ++it) {
            int b_loc = it * 4 + hi;
            f32x4 v = *(const f32x4*)&myt[b_loc * 64 + ((lo ^ (b_loc & 15)) * 4)];
            int n = n0 + lo * 4;
            if (n + 3 < V_) {
                __builtin_nontemporal_store(v, (f32x4*)(out + (size_t)(rbase + b_loc) * V_ + n));
            }
        }
    }
}

extern "C" void kernel_launch(void* const* d_in, const int* in_sizes, int n_in,
                              void* d_out, int out_size, void* d_ws, size_t ws_size,
                              hipStream_t stream) {
    const int* ids      = (const int*)d_in[0];
    const int* msk      = (const int*)d_in[1];
    const float* emb    = (const float*)d_in[2];
    const float* attn_a = (const float*)d_in[3];
    const float* attn_b = (const float*)d_in[4];
    const float* rbias  = (const float*)d_in[5];
    float* out = (float*)d_out;

    unsigned short* aT      = (unsigned short*)d_ws;                     // 32 KB
    unsigned short* user_bf = (unsigned short*)((char*)d_ws + 32768);    // 512 KB
    unsigned short* emb_bf  = (unsigned short*)((char*)d_ws + 32768 + 524288);  // 12.8 MB
    int use_bf = (ws_size >= (size_t)(32768 + 524288 + 12800000)) ? 1 : 0;

    k_pre<<<use_bf ? 3126 : 1, 256, 0, stream>>>(emb, emb_bf, attn_a, aT, use_bf);
    k_user<<<2048, 256, 0, stream>>>(ids, msk, emb, emb_bf, aT, attn_b, user_bf, use_bf);
    k_logits<<<dim3(782, 4), 256, 0, stream>>>(user_bf, emb, emb_bf, rbias, out, use_bf);
}